// Round 9
// baseline (787.156 us; speedup 1.0000x reference)
//
#include <hip/hip_runtime.h>

// GCN 2-layer forward — bucket-grouped edge records + LDS-scatter aggregation.
// Bucket = dst >> 8  (391 buckets x 256 nodes).
//   k_bhist: bucket histogram (LDS-aggregated)
//   k_bscan: bucket base offsets
//   k_binA : scatter packed records (src<<8 | dstLocal) into bucket regions
//   k_ndeg : per-bucket node-degree histogram -> dinv
//   k_xw   : xws = (x @ W1) * dinv    [4-way k-split, 2 nodes/thread,
//                                      XOR-swizzled W1 LDS -> 0 bank conflicts]
//   k_agg1 : block=bucket; acc[256][16] seeded with xws self-term;
//            LDS-atomic scatter of xws[src]; h = relu(b1+dinv*acc); hsc = h*dinv
//   k_agg2 : same over hsc; fused W2 epilogue -> out
// d_out = [out (N*32) | h (N*16)]

#define NN 100000
#define NE 3200000
#define FIN 512
#define HID 16
#define NCLS 32
#define NB 391          // ceil(NN/256)
#define NBP 512         // padded bucket slots

// workspace element offsets (4-byte units)
#define OFF_BCNT  0                     // int [NBP]
#define OFF_BBASE (NBP)                 // int [NBP]
#define OFF_BPOS  (2*NBP)               // int [NBP]
#define OFF_DINV  (3*NBP)               // float [NN]
#define OFF_EP    (3*NBP + NN)          // u32 [NE] packed records
#define OFF_XWS   (3*NBP + NN + NE)     // float [NN*16]
#define OFF_HSC   (OFF_XWS + NN*16)     // float [NN*16]  (h * dinv)

__global__ __launch_bounds__(512) void k_zeroB(int* __restrict__ bcnt) {
    bcnt[threadIdx.x] = 0;
}

__global__ __launch_bounds__(256) void k_bhist(const int* __restrict__ dst,
                                               int* __restrict__ bcnt) {
    __shared__ int h[NBP];
    for (int t = threadIdx.x; t < NBP; t += 256) h[t] = 0;
    __syncthreads();
    int stride = gridDim.x * 256;
    for (int e = blockIdx.x * 256 + threadIdx.x; e < NE; e += stride)
        atomicAdd(&h[dst[e] >> 8], 1);
    __syncthreads();
    for (int t = threadIdx.x; t < NB; t += 256)
        if (h[t]) atomicAdd(&bcnt[t], h[t]);
}

__global__ __launch_bounds__(512) void k_bscan(const int* __restrict__ bcnt,
                                               int* __restrict__ bbase,
                                               int* __restrict__ bpos) {
    __shared__ int s[512];
    int tid = threadIdx.x;
    int v = (tid < NB) ? bcnt[tid] : 0;
    s[tid] = v;
    __syncthreads();
#pragma unroll
    for (int o = 1; o < 512; o <<= 1) {
        int u = (tid >= o) ? s[tid - o] : 0;
        __syncthreads();
        s[tid] += u;
        __syncthreads();
    }
    int ex = s[tid] - v;
    if (tid < NB) { bbase[tid] = ex; bpos[tid] = ex; }
}

// Bin edges into bucket regions. 512 thr/block, 16 edges/thread, 8192/block.
__global__ __launch_bounds__(512) void k_binA(const int* __restrict__ src,
                                              const int* __restrict__ dst,
                                              int* __restrict__ bpos,
                                              unsigned* __restrict__ ep) {
    __shared__ int hist[NBP];
    __shared__ int gpos[NBP];
    int tid = threadIdx.x;
    hist[tid] = 0;
    __syncthreads();
    int base = blockIdx.x * 8192;
    unsigned rec[16];
    int meta[16];                       // (p_local << 9) | bucket, or -1
#pragma unroll
    for (int k = 0; k < 16; ++k) {
        int e = base + tid + k * 512;
        if (e < NE) {
            int s = src[e], d = dst[e];
            int b = d >> 8;
            int p = atomicAdd(&hist[b], 1);
            rec[k] = ((unsigned)s << 8) | (unsigned)(d & 255);
            meta[k] = (p << 9) | b;
        } else meta[k] = -1;
    }
    __syncthreads();
    int v = hist[tid];
    if (v > 0) gpos[tid] = atomicAdd(&bpos[tid], v);
    __syncthreads();
#pragma unroll
    for (int k = 0; k < 16; ++k) {
        if (meta[k] >= 0) {
            int b = meta[k] & 511;
            int p = meta[k] >> 9;
            ep[gpos[b] + p] = rec[k];
        }
    }
}

// Per-bucket node degree -> dinv.
__global__ __launch_bounds__(1024) void k_ndeg(const unsigned* __restrict__ ep,
                                               const int* __restrict__ bbase,
                                               const int* __restrict__ bcnt,
                                               float* __restrict__ dinv) {
    __shared__ int nh[256];
    int tid = threadIdx.x, b = blockIdx.x;
    if (tid < 256) nh[tid] = 0;
    __syncthreads();
    int gbase = bbase[b], bc = bcnt[b];
    for (int e = tid; e < bc; e += 1024)
        atomicAdd(&nh[ep[gbase + e] & 255], 1);
    __syncthreads();
    if (tid < 256) {
        int node = b * 256 + tid;
        if (node < NN) dinv[node] = rsqrtf((float)(nh[tid] + 1));
    }
}

// GEMM1: 4-way k-split, 2 nodes per thread; XOR-swizzled W1 in LDS.
__global__ __launch_bounds__(256) void k_xw(const float* __restrict__ x,
                                            const float* __restrict__ W1,
                                            const float* __restrict__ dinv,
                                            float* __restrict__ xws) {
    __shared__ float w1[FIN * HID];     // 32 KB, XOR-swizzled float4 blocks
    for (int t = threadIdx.x; t < FIN * HID; t += 256) {
        int k = t >> 4, j = t & 15;
        int s = (k * 4 + ((j >> 2) ^ ((k >> 2) & 3))) * 4 + (j & 3);
        w1[s] = W1[t];
    }
    __syncthreads();
    int w  = threadIdx.x >> 6;          // wave in block (0..3)
    int nl = (threadIdx.x >> 2) & 15;   // node slot
    int c  = threadIdx.x & 3;           // k-split group
    int n0 = blockIdx.x * 128 + w * 32 + nl;
    int n1 = n0 + 16;
    bool v0 = n0 < NN, v1 = n1 < NN;
    const float4* x4 = reinterpret_cast<const float4*>(x);
    const float4* r0 = x4 + (v0 ? (size_t)n0 * (FIN / 4) : 0);
    const float4* r1 = x4 + (v1 ? (size_t)n1 * (FIN / 4) : 0);
    const float4* wv = reinterpret_cast<const float4*>(w1);
    float a0[HID], a1[HID];
#pragma unroll
    for (int j = 0; j < HID; ++j) { a0[j] = 0.f; a1[j] = 0.f; }
#pragma unroll 4
    for (int t = 0; t < 32; ++t) {
        int qk = c + 4 * t;             // float4-quad index into the row
        float4 xv0 = r0[qk];
        float4 xv1 = r1[qk];
        const float4* wb = wv + qk * 16;
#pragma unroll
        for (int e = 0; e < 4; ++e) {
            float xe0 = (e == 0) ? xv0.x : (e == 1) ? xv0.y : (e == 2) ? xv0.z : xv0.w;
            float xe1 = (e == 0) ? xv1.x : (e == 1) ? xv1.y : (e == 2) ? xv1.z : xv1.w;
#pragma unroll
            for (int j4 = 0; j4 < 4; ++j4) {
                float4 w4 = wb[e * 4 + (j4 ^ c)];   // true w1[k][j4*4..+3]
                a0[j4 * 4 + 0] += xe0 * w4.x;
                a0[j4 * 4 + 1] += xe0 * w4.y;
                a0[j4 * 4 + 2] += xe0 * w4.z;
                a0[j4 * 4 + 3] += xe0 * w4.w;
                a1[j4 * 4 + 0] += xe1 * w4.x;
                a1[j4 * 4 + 1] += xe1 * w4.y;
                a1[j4 * 4 + 2] += xe1 * w4.z;
                a1[j4 * 4 + 3] += xe1 * w4.w;
            }
        }
    }
#pragma unroll
    for (int j = 0; j < HID; ++j) {
        a0[j] += __shfl_xor(a0[j], 1);
        a0[j] += __shfl_xor(a0[j], 2);
        a1[j] += __shfl_xor(a1[j], 1);
        a1[j] += __shfl_xor(a1[j], 2);
    }
    if (c == 0) {
        if (v0) {
            float dv = dinv[n0];
            float4* o = reinterpret_cast<float4*>(xws + (size_t)n0 * HID);
#pragma unroll
            for (int j4 = 0; j4 < 4; ++j4)
                o[j4] = make_float4(a0[j4 * 4 + 0] * dv, a0[j4 * 4 + 1] * dv,
                                    a0[j4 * 4 + 2] * dv, a0[j4 * 4 + 3] * dv);
        }
        if (v1) {
            float dv = dinv[n1];
            float4* o = reinterpret_cast<float4*>(xws + (size_t)n1 * HID);
#pragma unroll
            for (int j4 = 0; j4 < 4; ++j4)
                o[j4] = make_float4(a1[j4 * 4 + 0] * dv, a1[j4 * 4 + 1] * dv,
                                    a1[j4 * 4 + 2] * dv, a1[j4 * 4 + 3] * dv);
        }
    }
}

// Aggregation layer 1: block = bucket. acc[256][16] in LDS, seeded with the
// self-loop term xws[node]. Threads stream the bucket's records: 16-lane
// groups load one record (broadcast), gather one 64B xws row, ds_add_f32.
// Epilogue: h = relu(b1 + dinv*acc); hsc = h*dinv.
__global__ __launch_bounds__(1024) void k_agg1(const unsigned* __restrict__ ep,
                                               const int* __restrict__ bbase,
                                               const int* __restrict__ bcnt,
                                               const float* __restrict__ xws,
                                               const float* __restrict__ dinv,
                                               const float* __restrict__ b1,
                                               float* __restrict__ hout,
                                               float* __restrict__ hsc) {
    __shared__ float acc[256 * HID];    // 16 KB
    int tid = threadIdx.x, b = blockIdx.x;
    for (int t = tid; t < 256 * HID; t += 1024) {
        int node = b * 256 + (t >> 4);
        acc[t] = (node < NN) ? xws[node * HID + (t & 15)] : 0.f;
    }
    __syncthreads();
    int gbase = bbase[b], bc = bcnt[b];
    int j = tid & 15;
    int el = tid >> 4;                  // 0..63
    int e = el;
    for (; e + 192 < bc; e += 256) {    // 4 independent records in flight
        unsigned r0 = ep[gbase + e];
        unsigned r1 = ep[gbase + e + 64];
        unsigned r2 = ep[gbase + e + 128];
        unsigned r3 = ep[gbase + e + 192];
        float v0 = xws[(r0 >> 8) * HID + j];
        float v1 = xws[(r1 >> 8) * HID + j];
        float v2 = xws[(r2 >> 8) * HID + j];
        float v3 = xws[(r3 >> 8) * HID + j];
        atomicAdd(&acc[(r0 & 255) * HID + j], v0);
        atomicAdd(&acc[(r1 & 255) * HID + j], v1);
        atomicAdd(&acc[(r2 & 255) * HID + j], v2);
        atomicAdd(&acc[(r3 & 255) * HID + j], v3);
    }
    for (; e < bc; e += 64) {
        unsigned r = ep[gbase + e];
        atomicAdd(&acc[(r & 255) * HID + j], xws[(r >> 8) * HID + j]);
    }
    __syncthreads();
    for (int t = tid; t < 256 * HID; t += 1024) {
        int node = b * 256 + (t >> 4);
        if (node < NN) {
            float dv = dinv[node];
            float v = b1[t & 15] + dv * acc[t];
            float hv = v > 0.f ? v : 0.f;
            hout[node * HID + (t & 15)] = hv;
            hsc[node * HID + (t & 15)] = hv * dv;
        }
    }
}

// Aggregation layer 2: same scatter over hsc, seeded with hsc self-term.
// Epilogue fuses W2: out[i][jo] = b2[jo] + dinv[i] * sum_k acc[i][k]*W2[k][jo].
__global__ __launch_bounds__(1024) void k_agg2(const unsigned* __restrict__ ep,
                                               const int* __restrict__ bbase,
                                               const int* __restrict__ bcnt,
                                               const float* __restrict__ hsc,
                                               const float* __restrict__ dinv,
                                               const float* __restrict__ W2,
                                               const float* __restrict__ b2,
                                               float* __restrict__ out) {
    __shared__ float acc[256 * HID];    // 16 KB
    __shared__ float w2s[HID * NCLS];   // 2 KB
    __shared__ float b2s[NCLS];
    int tid = threadIdx.x, b = blockIdx.x;
    if (tid < HID * NCLS) w2s[tid] = W2[tid];
    if (tid >= 1024 - NCLS) b2s[tid - (1024 - NCLS)] = b2[tid - (1024 - NCLS)];
    for (int t = tid; t < 256 * HID; t += 1024) {
        int node = b * 256 + (t >> 4);
        acc[t] = (node < NN) ? hsc[node * HID + (t & 15)] : 0.f;
    }
    __syncthreads();
    int gbase = bbase[b], bc = bcnt[b];
    int j = tid & 15;
    int el = tid >> 4;
    int e = el;
    for (; e + 192 < bc; e += 256) {
        unsigned r0 = ep[gbase + e];
        unsigned r1 = ep[gbase + e + 64];
        unsigned r2 = ep[gbase + e + 128];
        unsigned r3 = ep[gbase + e + 192];
        float v0 = hsc[(r0 >> 8) * HID + j];
        float v1 = hsc[(r1 >> 8) * HID + j];
        float v2 = hsc[(r2 >> 8) * HID + j];
        float v3 = hsc[(r3 >> 8) * HID + j];
        atomicAdd(&acc[(r0 & 255) * HID + j], v0);
        atomicAdd(&acc[(r1 & 255) * HID + j], v1);
        atomicAdd(&acc[(r2 & 255) * HID + j], v2);
        atomicAdd(&acc[(r3 & 255) * HID + j], v3);
    }
    for (; e < bc; e += 64) {
        unsigned r = ep[gbase + e];
        atomicAdd(&acc[(r & 255) * HID + j], hsc[(r >> 8) * HID + j]);
    }
    __syncthreads();
    for (int t = tid; t < 256 * NCLS; t += 1024) {
        int nl = t >> 5, jo = t & 31;
        int node = b * 256 + nl;
        if (node < NN) {
            float s = 0.f;
#pragma unroll
            for (int k = 0; k < HID; ++k)
                s += acc[nl * HID + k] * w2s[k * NCLS + jo];
            out[node * NCLS + jo] = b2s[jo] + dinv[node] * s;
        }
    }
}

extern "C" void kernel_launch(void* const* d_in, const int* in_sizes, int n_in,
                              void* d_out, int out_size, void* d_ws, size_t ws_size,
                              hipStream_t stream) {
    const float* x  = (const float*)d_in[0];
    const int* ei   = (const int*)d_in[1];      // [2][NE]
    const float* W1 = (const float*)d_in[2];
    const float* b1 = (const float*)d_in[3];
    const float* W2 = (const float*)d_in[4];
    const float* b2 = (const float*)d_in[5];

    const int* src = ei;
    const int* dst = ei + NE;

    int* wsi = (int*)d_ws;
    int*      bcnt  = wsi + OFF_BCNT;
    int*      bbase = wsi + OFF_BBASE;
    int*      bpos  = wsi + OFF_BPOS;
    float*    dinv  = (float*)(wsi + OFF_DINV);
    unsigned* ep    = (unsigned*)(wsi + OFF_EP);   // packed records
    float*    xws   = (float*)(wsi + OFF_XWS);
    float*    hsc   = (float*)(wsi + OFF_HSC);

    float* outp = (float*)d_out;           // [NN*32]
    float* hout = outp + NN * NCLS;        // [NN*16]

    const int B = 256;

    hipLaunchKernelGGL(k_zeroB, dim3(1), dim3(512), 0, stream, bcnt);
    hipLaunchKernelGGL(k_bhist, dim3(512), dim3(B), 0, stream, dst, bcnt);
    hipLaunchKernelGGL(k_bscan, dim3(1), dim3(512), 0, stream, bcnt, bbase, bpos);
    hipLaunchKernelGGL(k_binA,  dim3((NE + 8191) / 8192), dim3(512), 0, stream, src, dst, bpos, ep);
    hipLaunchKernelGGL(k_ndeg,  dim3(NB), dim3(1024), 0, stream, ep, bbase, bcnt, dinv);
    hipLaunchKernelGGL(k_xw,    dim3((NN + 127) / 128), dim3(B), 0, stream, x, W1, dinv, xws);
    hipLaunchKernelGGL(k_agg1,  dim3(NB), dim3(1024), 0, stream, ep, bbase, bcnt, xws, dinv, b1, hout, hsc);
    hipLaunchKernelGGL(k_agg2,  dim3(NB), dim3(1024), 0, stream, ep, bbase, bcnt, hsc, dinv, W2, b2, outp);
}

// Round 10
// 222.953 us; speedup vs baseline: 3.5306x; 3.5306x over previous
//
#include <hip/hip_runtime.h>

// GCN 2-layer forward, CSR-gather with fixed-capacity radix binning.
// Bucket = dst >> 8  (391 buckets x 256 nodes), fixed region of CAP_B slots.
//   k_zeroB: zero bucket counters
//   k_binA : scatter packed records (src<<8 | dstLocal) into bucket regions,
//            reserving space via one global atomic per (block,bucket)
//   k_binB : per-bucket CSR build in LDS -> esrc (in-place), start, cnt, dinv
//   k_xw   : xws = (x @ W1) * dinv    [4-way k-split, 2 nodes/thread,
//                                      XOR-swizzled W1 LDS -> 0 bank conflicts]
//   k_gather1 : h = relu(b1 + dinv*(sum xws[src] + xws[i]));  hsc = h*dinv
//   k_gather2h: out = b2 + dinv*((sum hsc[src] + hsc[i]) @ W2)   [fused W2]
// d_out = [out (N*32) | h (N*16)]

#define NN 100000
#define NE 3200000
#define FIN 512
#define HID 16
#define NCLS 32
#define NB 391          // ceil(NN/256)
#define NBP 512         // padded bucket slots
#define CAP_B 9216      // fixed slots per bucket (mean 8184, +11 sigma)

// workspace element offsets (4-byte units)
#define OFF_BCNT  0                     // int [NBP]
#define OFF_START (NBP)                 // int [NN]
#define OFF_CNT   (NBP + NN)            // int [NN]
#define OFF_DINV  (NBP + 2*NN)          // float [NN]
#define OFF_EP    (NBP + 3*NN)          // u32 [NB*CAP_B]; becomes esrc
#define OFF_XWS   (OFF_EP + NB*CAP_B)   // float [NN*16]
#define OFF_HSC   (OFF_XWS + NN*16)     // float [NN*16]  (h * dinv)

__global__ __launch_bounds__(512) void k_zeroB(int* __restrict__ bcnt) {
    bcnt[threadIdx.x] = 0;
}

// Bin edges into fixed-cap bucket regions. 512 thr/block, 16 edges/thread.
__global__ __launch_bounds__(512) void k_binA(const int* __restrict__ src,
                                              const int* __restrict__ dst,
                                              int* __restrict__ bcnt,
                                              unsigned* __restrict__ ep) {
    __shared__ int hist[NBP];
    __shared__ int gpos[NBP];
    int tid = threadIdx.x;
    hist[tid] = 0;
    __syncthreads();
    int base = blockIdx.x * 8192;
    unsigned rec[16];
    int meta[16];                       // (p_local << 9) | bucket, or -1
#pragma unroll
    for (int k = 0; k < 16; ++k) {
        int e = base + tid + k * 512;
        if (e < NE) {
            int s = src[e], d = dst[e];
            int b = d >> 8;
            int p = atomicAdd(&hist[b], 1);
            rec[k] = ((unsigned)s << 8) | (unsigned)(d & 255);
            meta[k] = (p << 9) | b;
        } else meta[k] = -1;
    }
    __syncthreads();
    int v = hist[tid];
    if (v > 0) gpos[tid] = atomicAdd(&bcnt[tid], v);   // direct reservation
    __syncthreads();
#pragma unroll
    for (int k = 0; k < 16; ++k) {
        if (meta[k] >= 0) {
            int b = meta[k] & 511;
            int p = meta[k] >> 9;
            ep[b * CAP_B + gpos[b] + p] = rec[k];
        }
    }
}

// Per-bucket CSR build in LDS. Block b owns nodes [b*256, b*256+256).
__global__ __launch_bounds__(256) void k_binB(unsigned* __restrict__ ep,
                                              const int* __restrict__ bcnt,
                                              int* __restrict__ startA,
                                              int* __restrict__ cntA,
                                              float* __restrict__ dinv) {
    __shared__ int nh[256];
    __shared__ int ns[256];
    __shared__ int np_[256];
    __shared__ int esL[CAP_B];
    int tid = threadIdx.x;
    int b = blockIdx.x;
    int gbase = b * CAP_B;
    int bc = bcnt[b];
    if (bc > CAP_B) bc = CAP_B;         // defensive clamp
    nh[tid] = 0;
    __syncthreads();
    for (int t = tid; t < bc; t += 256)
        atomicAdd(&nh[ep[gbase + t] & 255], 1);
    __syncthreads();
    int v = nh[tid];
    ns[tid] = v;
    __syncthreads();
#pragma unroll
    for (int o = 1; o < 256; o <<= 1) {
        int u = (tid >= o) ? ns[tid - o] : 0;
        __syncthreads();
        ns[tid] += u;
        __syncthreads();
    }
    int ex = ns[tid] - v;               // exclusive start within bucket
    np_[tid] = ex;
    __syncthreads();
    for (int t = tid; t < bc; t += 256) {
        unsigned r = ep[gbase + t];
        int dl = r & 255;
        int p = atomicAdd(&np_[dl], 1);
        esL[p] = (int)(r >> 8);
    }
    __syncthreads();
    for (int t = tid; t < bc; t += 256)
        ep[gbase + t] = (unsigned)esL[t];   // in-place: ep becomes esrc
    int node = b * 256 + tid;
    if (node < NN) {
        startA[node] = gbase + ex;
        cntA[node]   = v;
        dinv[node]   = rsqrtf((float)(v + 1));
    }
}

// GEMM1: 4-way k-split, 2 nodes per thread.
// Wave = 32 nodes: nl = (tid>>2)&15 -> nodes (base+nl, base+nl+16); c = tid&3.
// Global: 4 lanes (c=0..3, same nl) read 4 consecutive float4s -> 64B segments.
// LDS: W1 float4 slot (k*4 + (j4 ^ ((k>>2)&3))) -> conflict-free broadcasts.
__global__ __launch_bounds__(256) void k_xw(const float* __restrict__ x,
                                            const float* __restrict__ W1,
                                            const float* __restrict__ dinv,
                                            float* __restrict__ xws) {
    __shared__ float w1[FIN * HID];     // 32 KB, XOR-swizzled float4 blocks
    for (int t = threadIdx.x; t < FIN * HID; t += 256) {
        int k = t >> 4, j = t & 15;
        int s = (k * 4 + ((j >> 2) ^ ((k >> 2) & 3))) * 4 + (j & 3);
        w1[s] = W1[t];
    }
    __syncthreads();
    int w  = threadIdx.x >> 6;          // wave in block (0..3)
    int nl = (threadIdx.x >> 2) & 15;   // node slot
    int c  = threadIdx.x & 3;           // k-split group
    int n0 = blockIdx.x * 128 + w * 32 + nl;
    int n1 = n0 + 16;
    bool v0 = n0 < NN, v1 = n1 < NN;
    const float4* x4 = reinterpret_cast<const float4*>(x);
    const float4* r0 = x4 + (v0 ? (size_t)n0 * (FIN / 4) : 0);
    const float4* r1 = x4 + (v1 ? (size_t)n1 * (FIN / 4) : 0);
    const float4* wv = reinterpret_cast<const float4*>(w1);
    float a0[HID], a1[HID];
#pragma unroll
    for (int j = 0; j < HID; ++j) { a0[j] = 0.f; a1[j] = 0.f; }
#pragma unroll 4
    for (int t = 0; t < 32; ++t) {
        int qk = c + 4 * t;             // float4-quad index into the row
        float4 xv0 = r0[qk];
        float4 xv1 = r1[qk];
        const float4* wb = wv + qk * 16;
#pragma unroll
        for (int e = 0; e < 4; ++e) {
            float xe0 = (e == 0) ? xv0.x : (e == 1) ? xv0.y : (e == 2) ? xv0.z : xv0.w;
            float xe1 = (e == 0) ? xv1.x : (e == 1) ? xv1.y : (e == 2) ? xv1.z : xv1.w;
#pragma unroll
            for (int j4 = 0; j4 < 4; ++j4) {
                float4 w4 = wb[e * 4 + (j4 ^ c)];   // true w1[k][j4*4..+3]
                a0[j4 * 4 + 0] += xe0 * w4.x;
                a0[j4 * 4 + 1] += xe0 * w4.y;
                a0[j4 * 4 + 2] += xe0 * w4.z;
                a0[j4 * 4 + 3] += xe0 * w4.w;
                a1[j4 * 4 + 0] += xe1 * w4.x;
                a1[j4 * 4 + 1] += xe1 * w4.y;
                a1[j4 * 4 + 2] += xe1 * w4.z;
                a1[j4 * 4 + 3] += xe1 * w4.w;
            }
        }
    }
#pragma unroll
    for (int j = 0; j < HID; ++j) {
        a0[j] += __shfl_xor(a0[j], 1);
        a0[j] += __shfl_xor(a0[j], 2);
        a1[j] += __shfl_xor(a1[j], 1);
        a1[j] += __shfl_xor(a1[j], 2);
    }
    if (c == 0) {
        if (v0) {
            float dv = dinv[n0];
            float4* o = reinterpret_cast<float4*>(xws + (size_t)n0 * HID);
#pragma unroll
            for (int j4 = 0; j4 < 4; ++j4)
                o[j4] = make_float4(a0[j4 * 4 + 0] * dv, a0[j4 * 4 + 1] * dv,
                                    a0[j4 * 4 + 2] * dv, a0[j4 * 4 + 3] * dv);
        }
        if (v1) {
            float dv = dinv[n1];
            float4* o = reinterpret_cast<float4*>(xws + (size_t)n1 * HID);
#pragma unroll
            for (int j4 = 0; j4 < 4; ++j4)
                o[j4] = make_float4(a1[j4 * 4 + 0] * dv, a1[j4 * 4 + 1] * dv,
                                    a1[j4 * 4 + 2] * dv, a1[j4 * 4 + 3] * dv);
        }
    }
}

// Gather layer 1: 1 node/wave, j = lane&15, 4-way edge parallel (c = lane>>4).
// MLP-4 unroll. Writes h (d_out) and hsc = h*dinv (workspace).
__global__ __launch_bounds__(256) void k_gather1(const int* __restrict__ startA,
                                                 const int* __restrict__ cntA,
                                                 const int* __restrict__ esrc,
                                                 const float* __restrict__ xws,
                                                 const float* __restrict__ dinv,
                                                 const float* __restrict__ b1,
                                                 float* __restrict__ hout,
                                                 float* __restrict__ hsc) {
    int wave = (blockIdx.x * 256 + threadIdx.x) >> 6;
    if (wave >= NN) return;
    int i = wave;
    int lane = threadIdx.x & 63;
    int j = lane & 15;
    int c = lane >> 4;                  // 0..3
    int st = startA[i], en = st + cntA[i];
    float s0 = 0.f, s1 = 0.f, s2 = 0.f, s3 = 0.f;
    int e = st + c;
    for (; e + 12 < en; e += 16) {      // 16 edges/iter wave-wide, 4 per c-group
        int a0 = esrc[e];
        int a1 = esrc[e + 4];
        int a2 = esrc[e + 8];
        int a3 = esrc[e + 12];
        s0 += xws[a0 * HID + j];
        s1 += xws[a1 * HID + j];
        s2 += xws[a2 * HID + j];
        s3 += xws[a3 * HID + j];
    }
    for (; e < en; e += 4) s0 += xws[esrc[e] * HID + j];
    float sum = (s0 + s1) + (s2 + s3);
    sum += __shfl_xor(sum, 16);
    sum += __shfl_xor(sum, 32);
    if (c == 0) {
        float dv = dinv[i];
        float v = b1[j] + dv * (sum + xws[i * HID + j]);
        float hv = v > 0.f ? v : 0.f;
        hout[i * HID + j] = hv;
        hsc[i * HID + j] = hv * dv;
    }
}

// Gather layer 2 with fused W2: 1 node/wave, j = lane&15, 4-way edge parallel.
// Gathers hsc (16 floats/edge), reduces, then epilogue:
//   out[i][jo] = b2[jo] + dinv[i] * sum_k v[k] * W2[k][jo]
__global__ __launch_bounds__(256) void k_gather2h(const int* __restrict__ startA,
                                                  const int* __restrict__ cntA,
                                                  const int* __restrict__ esrc,
                                                  const float* __restrict__ hsc,
                                                  const float* __restrict__ dinv,
                                                  const float* __restrict__ W2,
                                                  const float* __restrict__ b2,
                                                  float* __restrict__ out) {
    __shared__ float w2s[HID * NCLS];
    __shared__ float b2s[NCLS];
    for (int t = threadIdx.x; t < HID * NCLS; t += 256) w2s[t] = W2[t];
    if (threadIdx.x < NCLS) b2s[threadIdx.x] = b2[threadIdx.x];
    __syncthreads();
    int wave = (blockIdx.x * 256 + threadIdx.x) >> 6;
    if (wave >= NN) return;
    int i = wave;
    int lane = threadIdx.x & 63;
    int j = lane & 15;
    int c = lane >> 4;                  // 0..3
    int st = startA[i], en = st + cntA[i];
    float s0 = 0.f, s1 = 0.f, s2 = 0.f, s3 = 0.f;
    int e = st + c;
    for (; e + 12 < en; e += 16) {      // 16 edges/iter wave-wide, 4 per c-group
        int a0 = esrc[e];
        int a1 = esrc[e + 4];
        int a2 = esrc[e + 8];
        int a3 = esrc[e + 12];
        s0 += hsc[a0 * HID + j];
        s1 += hsc[a1 * HID + j];
        s2 += hsc[a2 * HID + j];
        s3 += hsc[a3 * HID + j];
    }
    for (; e < en; e += 4) s0 += hsc[esrc[e] * HID + j];
    float sum = (s0 + s1) + (s2 + s3);
    sum += __shfl_xor(sum, 16);
    sum += __shfl_xor(sum, 32);
    sum += hsc[i * HID + j];            // self-loop term (uniform across replicas)
    // epilogue: out[jo] for jo = lane (lanes 0..31)
    int jo = lane & 31;
    float acc = 0.f;
#pragma unroll
    for (int k = 0; k < HID; ++k) {
        float vk = __shfl(sum, k);      // v[k] broadcast (readlane)
        acc += vk * w2s[k * NCLS + jo];
    }
    if (lane < 32)
        out[i * NCLS + jo] = b2s[jo] + dinv[i] * acc;
}

extern "C" void kernel_launch(void* const* d_in, const int* in_sizes, int n_in,
                              void* d_out, int out_size, void* d_ws, size_t ws_size,
                              hipStream_t stream) {
    const float* x  = (const float*)d_in[0];
    const int* ei   = (const int*)d_in[1];      // [2][NE]
    const float* W1 = (const float*)d_in[2];
    const float* b1 = (const float*)d_in[3];
    const float* W2 = (const float*)d_in[4];
    const float* b2 = (const float*)d_in[5];

    const int* src = ei;
    const int* dst = ei + NE;

    int* wsi = (int*)d_ws;
    int*      bcnt  = wsi + OFF_BCNT;
    int*      startA= wsi + OFF_START;
    int*      cntA  = wsi + OFF_CNT;
    float*    dinv  = (float*)(wsi + OFF_DINV);
    unsigned* ep    = (unsigned*)(wsi + OFF_EP);   // packed, then esrc
    float*    xws   = (float*)(wsi + OFF_XWS);
    float*    hsc   = (float*)(wsi + OFF_HSC);

    float* outp = (float*)d_out;           // [NN*32]
    float* hout = outp + NN * NCLS;        // [NN*16]

    const int B = 256;

    hipLaunchKernelGGL(k_zeroB, dim3(1), dim3(512), 0, stream, bcnt);
    hipLaunchKernelGGL(k_binA,  dim3((NE + 8191) / 8192), dim3(512), 0, stream, src, dst, bcnt, ep);
    hipLaunchKernelGGL(k_binB,  dim3(NB), dim3(B), 0, stream, ep, bcnt, startA, cntA, dinv);
    hipLaunchKernelGGL(k_xw,    dim3((NN + 127) / 128), dim3(B), 0, stream, x, W1, dinv, xws);
    hipLaunchKernelGGL(k_gather1, dim3((NN * 64 + B - 1) / B), dim3(B), 0, stream,
                       startA, cntA, (const int*)ep, xws, dinv, b1, hout, hsc);
    hipLaunchKernelGGL(k_gather2h, dim3((NN * 64 + B - 1) / B), dim3(B), 0, stream,
                       startA, cntA, (const int*)ep, hsc, dinv, W2, b2, outp);
}